// Round 7
// baseline (204.257 us; speedup 1.0000x reference)
//
#include <hip/hip_runtime.h>
#include <math.h>

typedef _Float16 f16x8 __attribute__((ext_vector_type(8)));
typedef float f32x4 __attribute__((ext_vector_type(4)));

#define CIN 8
#define HIN 128
#define WIN 128
#define OH 126
#define OW 126
#define COUT 64
#define NB 128
#define NGROUPS 16
#define CPG 4
#define PWN 31
#define XROWS 34
#define XH_DIM 130            // padded image (2 halo rows/cols of zeros)
#define TPIX (34*34)          // 1156 pixels per tile
#define XSPAD 3072            // pads LDS to 54.4KB -> 2 blocks/CU (proven R5 geometry)

// ---- ws layout (bytes) ----
// xh f16 [b][iy][ix][ci] | wext f16 [b][wy][wx][c] | parts f32
#define XH_BYTES   ((size_t)NB*XH_DIM*XH_DIM*CIN*2)          // 34,611,200
#define WEXT_BYTES ((size_t)NB*PWN*PWN*COUT*2)               // 15,745,024
#define PART_BYTES ((size_t)NB*NGROUPS*4*2*4)                //     65,536
#define WS_NEEDED  (XH_BYTES + WEXT_BYTES + PART_BYTES)

// ---- old (fallback) ws layout ----
#define NPOOL (NB*PWN*PWN*COUT)
#define OFF_PART_OLD (NPOOL/2)   // f32 offset

// ============================================================
// R7 = R6 fusion with the bias RESTORED.
// R6 failed (absmax 0.389) because "bias cancels through GN" is false:
// GroupNorm stats mix 4 channels with DIFFERENT biases, so dropping
// bias shifts group mean by avg(cb) != cb_c and changes group var by
// the cross-channel bias spread. Predicted error (cb_c-avg)/sigma*scale
// ~ 0.2-0.4 matches the measured 0.389 -> the pack-fusion pipeline
// itself is presumed correct and gets its clean test this round.
//
// Fusion recap (R6): each block packs its OWN 34-col x-stripe into xh
// in 34-row chunks interleaved with the tile loop (chunk T+2 packed
// during tile T compute; per-tile vmcnt(0)+barrier drains it before
// stage(T+2) reads it). Pack HBM traffic hides under compute (conv ran
// at 600 GB/s, 10x headroom). Halo double-writes across blocks write
// byte-identical values: benign.
// ============================================================
__global__ __launch_bounds__(512)
void conv_fused_kernel(const float* __restrict__ x,
                       const float* __restrict__ w,
                       const float* __restrict__ bias,
                       const float* __restrict__ gnw,
                       const float* __restrict__ scale,
                       _Float16* __restrict__ xh,
                       _Float16* __restrict__ wext,
                       float* __restrict__ parts)
{
  __shared__ __align__(16) _Float16 xs[2][TPIX*8 + XSPAD]; // 2 x 24,640 B
  __shared__ __align__(8)  _Float16 sbuf[8][256];          //   4,096 B
  __shared__ float red[8][16][2];                          //   1,024 B

  const int tid  = threadIdx.x;
  const int lane = tid & 63, wv = tid >> 6;     // 8 waves
  const int tx = blockIdx.x;                    // 0..3 (tile column)
  const int b  = blockIdx.y;
  const int ox0 = tx*32;
  const int q = lane >> 4, ln = lane & 15;

  // pack chunk T: rows 32T..32T+33 of this block's 34-col stripe -> xh
  const float* xb = x + (size_t)b * CIN*HIN*WIN;
  auto packchunk = [&](int T) {
    const int y0 = T*32;
    for (int p = tid; p < TPIX; p += 512) {     // 3 iterations
      const int r = p / 34, c = p - r*34;
      const int iy = y0 + r, ix = ox0 + c;
      f16x8 pk = {0,0,0,0,0,0,0,0};
      if (iy < HIN && ix < WIN) {
        const int gb = iy*WIN + ix;
        #pragma unroll
        for (int ci = 0; ci < 8; ++ci)
          pk[ci] = (_Float16)xb[ci*HIN*WIN + gb];
      }
      *(f16x8*)&xh[(((size_t)b*XH_DIM + iy)*XH_DIM + ix)*CIN] = pk;
    }
  };

  // DMA one tile into xs[buf]: one f16x8 pixel per lane per instr.
  auto stage = [&](int buf, int ty) {
    const int oy0 = ty*32;
    #pragma unroll
    for (int k = 0; k < 3; ++k) {
      const int p = k*512 + tid;
      if (p < TPIX) {
        const int r = p / 34, c = p - r*34;
        const size_t gb = (((size_t)b*XH_DIM + (oy0 + r))*XH_DIM + (ox0 + c))*CIN;
        __builtin_amdgcn_global_load_lds(
            (const __attribute__((address_space(1))) void*)(xh + gb),
            (__attribute__((address_space(3))) void*)&xs[buf][p*8],
            16, 0, 0);
      }
    }
  };

  // ---- prologue: pack chunks 0,1; B-frags from global w ----
  packchunk(0);
  packchunk(1);

  f16x8 bf[4][3];
  #pragma unroll
  for (int nt = 0; nt < 4; ++nt) {
    const int n = nt*16 + ln;
    #pragma unroll
    for (int c = 0; c < 2; ++c) {
      const int khw = c*4 + q;
      #pragma unroll
      for (int ci = 0; ci < 8; ++ci)
        bf[nt][c][ci] = (_Float16)w[(n*CIN + ci)*9 + khw];
    }
    if (q == 0) {
      #pragma unroll
      for (int ci = 0; ci < 8; ++ci)
        bf[nt][2][ci] = (_Float16)w[(n*CIN + ci)*9 + 8];
    } else {
      bf[nt][2] = (f16x8){0,0,0,0,0,0,0,0};
    }
  }

  // strip A offsets: lane ln = x-offset m, quad q picks khw = c*4+q.
  int aoff[3];
  #pragma unroll
  for (int c = 0; c < 3; ++c) {
    const int khw = c*4 + q;               // 0..11
    const int ky = khw / 3, kx = khw - 3*(khw/3);
    aoff[c] = (khw < 9) ? (ky*34 + kx + ln)*8 : ln*8;  // padded taps -> B=0
  }

  float bias_r[4], sgn[4];
  #pragma unroll
  for (int nt = 0; nt < 4; ++nt) {
    const int c = nt*16 + ln;
    bias_r[nt] = bias[c];
    sgn[nt] = (gnw[c]*scale[c] >= 0.f) ? 1.f : -1.f;  // GN slope sign (inv>0)
  }

  float s[4]  = {0.f,0.f,0.f,0.f};
  float sq[4] = {0.f,0.f,0.f,0.f};

  // stats x-mask: strip positions 14,15 (q==3, regs 2,3) are conv-x
  // 126,127 when tx==3 && bd==1 -> excluded.
  const float xm_hi = (q < 3) ? 1.f : 0.f;

  // chunks 0,1 + bf loads complete; visible block-wide
  asm volatile("s_waitcnt vmcnt(0)" ::: "memory");
  __syncthreads();
  stage(0, 0);
  asm volatile("s_waitcnt vmcnt(0)" ::: "memory");
  __syncthreads();

  for (int ty = 0; ty < 4; ++ty) {
    const int cur = ty & 1;
    if (ty < 3) stage(cur ^ 1, ty + 1);    // async prefetch next tile
    if (ty < 2) packchunk(ty + 2);         // pack 2 ahead, hidden under compute
    // note: chunk ty+2 overlaps tile ty+1's rows by 2 (same values) - benign

    const int wy_g = ty*8 + wv;
    const int oy0  = ty*32;

    // 2 bands per wave (x0 = 0, 16); band = 4 strips = 4 pool windows
    #pragma unroll
    for (int bd = 0; bd < 2; ++bd) {
      const int x0 = bd << 4;
      const bool xedge = (tx == 3) && (bd == 1);

      float mx[4] = {-1e30f, -1e30f, -1e30f, -1e30f};

      #pragma unroll
      for (int sy = 0; sy < 4; ++sy) {
        const int y_l = wv*4 + sy;
        if (oy0 + y_l >= OH) break;        // uniform: only ty==3, wv==7, sy>=2
        const int base = (y_l*34 + x0)*8;

        f32x4 acc[4];
        #pragma unroll
        for (int nt = 0; nt < 4; ++nt) {
          const float bv = bias_r[nt];
          acc[nt] = (f32x4){bv, bv, bv, bv};  // bias as MFMA C operand
        }
        #pragma unroll
        for (int c = 0; c < 3; ++c) {
          const f16x8 a = *(const f16x8*)&xs[cur][base + aoff[c]];
          #pragma unroll
          for (int nt = 0; nt < 4; ++nt)
            acc[nt] = __builtin_amdgcn_mfma_f32_16x16x32_f16(a, bf[nt][c], acc[nt], 0, 0, 0);
        }

        // fully in-lane: stats + running window max (sign-domain)
        #pragma unroll
        for (int nt = 0; nt < 4; ++nt) {
          float v0 = acc[nt][0], v1 = acc[nt][1];
          float v2 = acc[nt][2], v3 = acc[nt][3];
          if (xedge) { v2 *= xm_hi; v3 *= xm_hi; }   // mask conv-x 126,127
          s[nt]  += (v0+v1) + (v2+v3);
          sq[nt] += v0*v0 + v1*v1 + v2*v2 + v3*v3;
          const float sg = sgn[nt];
          const float m = fmaxf(fmaxf(sg*v0, sg*v1), fmaxf(sg*v2, sg*v3));
          mx[nt] = fmaxf(mx[nt], m);
        }
      }

      // store band's 4 pooled windows: sbuf bounce -> coalesced store
      if (wy_g < PWN) {
        #pragma unroll
        for (int nt = 0; nt < 4; ++nt)
          sbuf[wv][q*64 + nt*16 + ln] = (_Float16)(sgn[nt]*mx[nt]);
        const int nw = xedge ? 3 : 4;      // window wx_g==31 dropped
        if (lane < nw*16) {
          const int wx0_g = tx*8 + (x0 >> 2);
          const uint2 v = *(const uint2*)&sbuf[wv][lane*4];
          *(uint2*)&wext[(((size_t)b*PWN + wy_g)*PWN + wx0_g)*COUT + lane*4] = v;
        }
      }
    }

    if (ty < 3) {
      asm volatile("s_waitcnt vmcnt(0)" ::: "memory");  // next-tile DMA + pack stores done
      __syncthreads();                                   // visible to all waves
    }
  }

  // per-wave stat reduce: quads (xor 16,32) then channels-in-group (xor 1,2)
  #pragma unroll
  for (int nt = 0; nt < 4; ++nt) {
    float a = s[nt], c2 = sq[nt];
    a  += __shfl_xor(a, 16, 64);  a  += __shfl_xor(a, 32, 64);
    a  += __shfl_xor(a, 1, 64);   a  += __shfl_xor(a, 2, 64);
    c2 += __shfl_xor(c2, 16, 64); c2 += __shfl_xor(c2, 32, 64);
    c2 += __shfl_xor(c2, 1, 64);  c2 += __shfl_xor(c2, 2, 64);
    if (lane < 16 && (lane & 3) == 0) {
      red[wv][nt*4 + (ln >> 2)][0] = a;
      red[wv][nt*4 + (ln >> 2)][1] = c2;
    }
  }
  __syncthreads();
  if (tid < 32) {
    const int g = tid >> 1, k = tid & 1;
    float t = 0.f;
    #pragma unroll
    for (int w8 = 0; w8 < 8; ++w8) t += red[w8][g][k];
    parts[(((size_t)b*NGROUPS + g)*4 + tx)*2 + k] = t;
  }
}

// ============================================================
// Fallback conv (proven R0/R2 path, old ws layout; keeps bias).
// ============================================================
__global__ __launch_bounds__(256)
void conv_mfma_kernel(const float* __restrict__ x,
                      const float* __restrict__ w,
                      const float* __restrict__ bias,
                      const float* __restrict__ gnw,
                      const float* __restrict__ scale,
                      float* __restrict__ ws)
{
  __shared__ __align__(16) _Float16 xs[XROWS*34*8];
  __shared__ __align__(16) _Float16 wls[9*64*8];
  __shared__ float red[4][16][2];

  const int tid  = threadIdx.x;
  const int lane = tid & 63, wave = tid >> 6;
  const int tileIdx = blockIdx.x;
  const int tx = tileIdx & 3, ty = tileIdx >> 2;
  const int b  = blockIdx.y;
  const int ox0 = tx*32, oy0 = ty*32;

  for (int idx = tid; idx < 9*64*8; idx += 256) {
    const int ci = idx & 7, n = (idx >> 3) & 63, khw = idx >> 9;
    wls[idx] = (_Float16)w[(n*CIN + ci)*9 + khw];
  }
  const float* xb = x + (size_t)b * CIN*HIN*WIN;
  for (int p = tid; p < XROWS*34; p += 256) {
    const int r = p / 34, c = p - r*34;
    const int iy = oy0 + r, ix = ox0 + c;
    const bool ok = (iy < HIN) && (ix < WIN);
    const int gbase = iy*WIN + ix;
    f16x8 pk;
    #pragma unroll
    for (int ci = 0; ci < 8; ++ci) {
      const float v = ok ? xb[ci*HIN*WIN + gbase] : 0.f;
      pk[ci] = (_Float16)v;
    }
    *(f16x8*)&xs[p*8] = pk;
  }
  __syncthreads();

  const int q = lane >> 4, ln = lane & 15;
  f16x8 bf[4][3];
  #pragma unroll
  for (int nt = 0; nt < 4; ++nt) {
    #pragma unroll
    for (int c = 0; c < 2; ++c)
      bf[nt][c] = *(const f16x8*)&wls[((c*4 + q)*64 + nt*16 + ln)*8];
    if (q == 0) bf[nt][2] = *(const f16x8*)&wls[((8)*64 + nt*16 + ln)*8];
    else        bf[nt][2] = (f16x8){0,0,0,0,0,0,0,0};
  }
  const int dy = ln >> 2, dx = ln & 3;
  int aoff[3];
  #pragma unroll
  for (int c = 0; c < 3; ++c) {
    const int khw = c*4 + q;
    const int ky = khw / 3, kx = khw - 3*(khw/3);
    aoff[c] = (khw < 9) ? ((dy + ky)*34 + (dx + kx))*8 : 0;
  }
  float bias_r[4], sgn[4];
  #pragma unroll
  for (int nt = 0; nt < 4; ++nt) {
    const int c = nt*16 + ln;
    bias_r[nt] = bias[c];
    sgn[nt] = (gnw[c]*scale[c] >= 0.f) ? 1.f : -1.f;
  }
  float s[4]  = {0.f,0.f,0.f,0.f};
  float sq[4] = {0.f,0.f,0.f,0.f};
  _Float16* wext = (_Float16*)ws;

  #pragma unroll 2
  for (int i = 0; i < 16; ++i) {
    const int wyl = wave*2 + (i >> 3), wxl = i & 7;
    const int base = (wyl*4*34 + wxl*4)*8;
    f32x4 acc[4];
    #pragma unroll
    for (int nt = 0; nt < 4; ++nt) {
      const float bv = bias_r[nt];
      acc[nt] = (f32x4){bv, bv, bv, bv};
    }
    #pragma unroll
    for (int c = 0; c < 3; ++c) {
      const f16x8 a = *(const f16x8*)&xs[base + aoff[c]];
      #pragma unroll
      for (int nt = 0; nt < 4; ++nt)
        acc[nt] = __builtin_amdgcn_mfma_f32_16x16x32_f16(a, bf[nt][c], acc[nt], 0, 0, 0);
    }
    const int wyg = ty*8 + wyl, wxg = tx*8 + wxl;
    if ((wyg < PWN) && (wxg < PWN)) {
      const size_t rowbase = ((size_t)(b*PWN + wyg)*PWN + wxg)*COUT;
      float m4[4];
      #pragma unroll
      for (int nt = 0; nt < 4; ++nt) {
        const float v0 = acc[nt][0], v1 = acc[nt][1];
        const float v2 = acc[nt][2], v3 = acc[nt][3];
        s[nt]  += (v0+v1) + (v2+v3);
        sq[nt] += v0*v0 + v1*v1 + v2*v2 + v3*v3;
        const float sg = sgn[nt];
        float m = fmaxf(fmaxf(sg*v0, sg*v1), fmaxf(sg*v2, sg*v3));
        m = fmaxf(m, __shfl_xor(m, 16, 64));
        m = fmaxf(m, __shfl_xor(m, 32, 64));
        m4[nt] = sg*m;
      }
      float mv = m4[0];
      mv = (q == 1) ? m4[1] : mv;
      mv = (q == 2) ? m4[2] : mv;
      mv = (q == 3) ? m4[3] : mv;
      wext[rowbase + lane] = (_Float16)mv;
    } else {
      const bool yv = (wyg*4 + q) < OH;
      #pragma unroll
      for (int nt = 0; nt < 4; ++nt) {
        #pragma unroll
        for (int r = 0; r < 4; ++r) {
          const bool okp = yv && (wxg*4 + r < OW);
          const float v = okp ? acc[nt][r] : 0.f;
          s[nt] += v; sq[nt] += v*v;
        }
      }
    }
  }
  #pragma unroll
  for (int nt = 0; nt < 4; ++nt) {
    float a = s[nt], c2 = sq[nt];
    a  += __shfl_xor(a, 16, 64);  a  += __shfl_xor(a, 32, 64);
    a  += __shfl_xor(a, 1, 64);   a  += __shfl_xor(a, 2, 64);
    c2 += __shfl_xor(c2, 16, 64); c2 += __shfl_xor(c2, 32, 64);
    c2 += __shfl_xor(c2, 1, 64);  c2 += __shfl_xor(c2, 2, 64);
    if (lane < 16 && (lane & 3) == 0) {
      red[wave][nt*4 + (ln >> 2)][0] = a;
      red[wave][nt*4 + (ln >> 2)][1] = c2;
    }
  }
  __syncthreads();
  if (tid < 32) {
    const int g = tid >> 1, k = tid & 1;
    const float t = red[0][g][k] + red[1][g][k] + red[2][g][k] + red[3][g][k];
    ws[OFF_PART_OLD + (((size_t)b*NGROUPS + g)*16 + tileIdx)*2 + k] = t;
  }
}

// ============================================================
// Fused tail (parameterized partial count / pointers). Unchanged.
// ============================================================
__global__ __launch_bounds__(256)
void tail_kernel(const float* __restrict__ gnw,
                 const float* __restrict__ gnb,
                 const float* __restrict__ scale,
                 const _Float16* __restrict__ wext,
                 const float* __restrict__ parts,
                 const int nparts,
                 float* __restrict__ out)
{
  __shared__ float stat[NGROUPS*2];
  __shared__ float AB[128];
  __shared__ float vout[COUT*PWN];

  const int tid = threadIdx.x;
  const int xb  = blockIdx.x;
  const int b   = blockIdx.y;

  if (tid < 32) {
    const int g = tid >> 1, k = tid & 1;
    const float* p = parts + ((size_t)(b*NGROUPS + g)*nparts)*2 + k;
    float a = 0.f;
    for (int t = 0; t < nparts; ++t) a += p[t*2];
    stat[g*2 + k] = a;
  }
  __syncthreads();
  if (tid < COUT) {
    const int c = tid, g = c >> 2;
    const float N = (float)(CPG * OH * OW);
    const float mean = stat[g*2] / N;
    const float var  = stat[g*2 + 1] / N - mean*mean;
    const float inv  = rsqrtf(var + 1e-5f);
    const float ag   = inv * gnw[c];
    AB[c]      = ag * scale[c];
    AB[64 + c] = (gnb[c] - mean * ag) * scale[c];
  }
  __syncthreads();

  #pragma unroll
  for (int r = 0; r < 2; ++r) {
    const int wy = xb*2 + r;
    if (wy >= PWN) break;
    const size_t rb = (size_t)(b*PWN + wy)*PWN*COUT;

    if (tid < 248) {
      const f16x8 e = *(const f16x8*)&wext[rb + tid*8];
      const int wx = tid >> 3, c0 = (tid & 7)*8;
      #pragma unroll
      for (int j = 0; j < 8; ++j) {
        const int c = c0 + j;
        float v = fmaf(AB[c], (float)e[j], AB[64 + c]);
        v = fminf(fmaxf(v, 0.f), 1.f);
        vout[c*PWN + wx] = v;
      }
    }
    __syncthreads();
    for (int e = tid; e < COUT*PWN; e += 256) {
      const int c = e / PWN, wx = e - c*PWN;
      out[(((size_t)b*COUT + c)*PWN + wy)*PWN + wx] = vout[e];
    }
    __syncthreads();
  }
}

extern "C" void kernel_launch(void* const* d_in, const int* in_sizes, int n_in,
                              void* d_out, int out_size, void* d_ws, size_t ws_size,
                              hipStream_t stream)
{
  const float* x     = (const float*)d_in[0];
  const float* cw    = (const float*)d_in[1];
  const float* cb    = (const float*)d_in[2];
  const float* gnw   = (const float*)d_in[3];
  const float* gnb   = (const float*)d_in[4];
  const float* scale = (const float*)d_in[5];
  float* out = (float*)d_out;
  float* ws  = (float*)d_ws;

  if (ws_size >= WS_NEEDED) {
    _Float16* xh   = (_Float16*)ws;
    _Float16* wext = (_Float16*)((char*)ws + XH_BYTES);
    float*    prt  = (float*)((char*)ws + XH_BYTES + WEXT_BYTES);

    conv_fused_kernel<<<dim3(4, NB), 512, 0, stream>>>(x, cw, cb, gnw, scale, xh, wext, prt);
    tail_kernel<<<dim3(16, NB), 256, 0, stream>>>(gnw, gnb, scale, wext, prt, 4, out);
  } else {
    conv_mfma_kernel<<<dim3(16, NB), 256, 0, stream>>>(x, cw, cb, gnw, scale, ws);
    tail_kernel<<<dim3(16, NB), 256, 0, stream>>>(gnw, gnb, scale,
                                                  (const _Float16*)ws,
                                                  ws + OFF_PART_OLD, 16, out);
  }
}